// Round 12
// baseline (105.427 us; speedup 1.0000x reference)
//
#include <hip/hip_runtime.h>
#include <hip/hip_cooperative_groups.h>

namespace cg = cooperative_groups;

#define G_TOTAL 16384            // 128 x 128 grid
#define NPTS    8192
#define CI      128              // context points per block chunk
#define NSPLIT  64               // 8192 / CI  -> grid 256 = 1 block/CU
#define LDA     136              // LDS row pitch in halves (128 + 8 pad)
#define PBLK    12288            // partial halves per block: 4w x 12f x 64l x 4r

typedef _Float16 f16;
typedef f16  f16x8 __attribute__((ext_vector_type(8)));
typedef f16  f16x4 __attribute__((ext_vector_type(4)));
typedef float f32x4 __attribute__((ext_vector_type(4)));

// Raw v_exp_f32 — args in [-40, 0]: no denormal/range fixup needed.
__device__ __forceinline__ float fast_exp2(float x) {
#if __has_builtin(__builtin_amdgcn_exp2f)
    return __builtin_amdgcn_exp2f(x);
#else
    float r; asm("v_exp_f32 %0, %1" : "=v"(r) : "v"(x)); return r;
#endif
}

// ---------------------------------------------------------------------------
// Fused cooperative kernel.
// R11 probe attribution: enc ~6us, reduce ~4, gaps ~3, harness overhead ~10,
// fill ~41. This round removes the 2nd launch (gap + dispatch) and gives the
// reduce 4x the blocks (256 vs 64) by fusing via grid.sync().
// Phase 1 = R10 enc verbatim (partials layout unchanged, 6.3MB fp16).
// Phase 2 = reduce: block bx=(tile,w,q,lh) covers 4k x 16j outputs; thread
// (l16 = t&15, sq = t>>4) sums 4 splits x 3 channels (coalesced h4 loads);
// 16-way LDS combine (reusing ExT space); 16 lanes normalize + write.
// ---------------------------------------------------------------------------
__global__ __launch_bounds__(256) void enc_reduce_coop(
    const float* __restrict__ X,   // (8192, 2) positions
    const float* __restrict__ Y,   // (8192, 2) labels
    f16* __restrict__ wsP,         // partials [tile][s][PBLK]
    float* __restrict__ out)       // (3, 16384)
{
    __shared__ f16 ExT[128 * LDA];     // [j][i]    34.8 KB  (phase2: reused)
    __shared__ f16 Ey3[3 * 32 * LDA];  // [c][k][i] 26.1 KB

    const int t    = threadIdx.x;
    const int b    = blockIdx.x;
    const int tile = b & 3;            // k band: kb = tile*32
    const int sidx = b >> 2;           // split 0..63
    const int c0   = sidx * CI;
    const int kb   = tile * 32;

    const float sc   = 0.84932184f;    // sqrt(0.5 * log2(e))
    const float step = 4.0f / 127.0f;

    const float2* X2 = (const float2*)X;
    const float2* Y2 = (const float2*)Y;

    // ---- stage ExT[j][i], fp16: thread -> (j = t>>1, 64-i half)
    {
        const int   j  = t >> 1, ih = (t & 1) * 64;
        const float gx = (-2.0f + step * (float)j) * sc;
#pragma unroll
        for (int u = 0; u < 8; ++u) {
            f16x8 v;
#pragma unroll
            for (int e = 0; e < 8; ++e) {
                const int   i = ih + u * 8 + e;
                const float d = gx - X2[c0 + i].x * sc;
                v[e] = (f16)fast_exp2(-d * d);
            }
            *(f16x8*)&ExT[j * LDA + ih + u * 8] = v;
        }
    }
    // ---- stage Ey3[c][k][i], channels baked: thread -> (k = t>>3, 16-i blk)
    {
        const int   k  = t >> 3, ib = (t & 7) * 16;
        const float gy = (2.0f - step * (float)(kb + k)) * sc;
#pragma unroll
        for (int u = 0; u < 2; ++u) {
            f16x8 v0, v1, v2;
#pragma unroll
            for (int e = 0; e < 8; ++e) {
                const int    i  = ib + u * 8 + e;
                const float  d  = gy - X2[c0 + i].y * sc;
                const float  ee = fast_exp2(-d * d);
                const float2 yv = Y2[c0 + i];
                v0[e] = (f16)ee;
                v1[e] = (f16)(ee * yv.x);
                v2[e] = (f16)(ee * yv.y);
            }
            *(f16x8*)&Ey3[(0 * 32 + k) * LDA + ib + u * 8] = v0;
            *(f16x8*)&Ey3[(1 * 32 + k) * LDA + ib + u * 8] = v1;
            *(f16x8*)&Ey3[(2 * 32 + k) * LDA + ib + u * 8] = v2;
        }
    }
    __syncthreads();

    // ---- MFMA: wave w owns j in [32w, 32w+32). 48 mfma per wave (4 ksteps).
    const int w    = t >> 6;
    const int lane = t & 63;
    const int l15  = lane & 15;
    const int lk8  = (lane >> 4) * 8;

    f32x4 acc[12];                     // [c*4 + kt*2 + jt]
#pragma unroll
    for (int z = 0; z < 12; ++z) acc[z] = (f32x4){0.f, 0.f, 0.f, 0.f};

#pragma unroll
    for (int ks = 0; ks < 4; ++ks) {
        const int io = ks * 32 + lk8;
        const f16x8 bf0 = *(const f16x8*)&ExT[(w * 32 +      l15) * LDA + io];
        const f16x8 bf1 = *(const f16x8*)&ExT[(w * 32 + 16 + l15) * LDA + io];
#pragma unroll
        for (int c = 0; c < 3; ++c) {
            const f16x8 a0 = *(const f16x8*)&Ey3[(c * 32 +      l15) * LDA + io];
            const f16x8 a1 = *(const f16x8*)&Ey3[(c * 32 + 16 + l15) * LDA + io];
            acc[c*4+0] = __builtin_amdgcn_mfma_f32_16x16x32_f16(a0, bf0, acc[c*4+0], 0, 0, 0);
            acc[c*4+1] = __builtin_amdgcn_mfma_f32_16x16x32_f16(a0, bf1, acc[c*4+1], 0, 0, 0);
            acc[c*4+2] = __builtin_amdgcn_mfma_f32_16x16x32_f16(a1, bf0, acc[c*4+2], 0, 0, 0);
            acc[c*4+3] = __builtin_amdgcn_mfma_f32_16x16x32_f16(a1, bf1, acc[c*4+3], 0, 0, 0);
        }
    }

    // ---- fragment-native fp16 partial store: lane-contiguous h4, coalesced.
    f16* P = wsP + (size_t)(tile * NSPLIT + sidx) * PBLK;
#pragma unroll
    for (int f = 0; f < 12; ++f) {
        f16x4 pv;
        pv[0] = (f16)acc[f][0];  pv[1] = (f16)acc[f][1];
        pv[2] = (f16)acc[f][2];  pv[3] = (f16)acc[f][3];
        *(f16x4*)&P[((w * 12 + f) * 64 + lane) * 4] = pv;
    }

    // ======================= grid-wide barrier =======================
    cg::this_grid().sync();

    // ---- phase 2: reduce + normalize across splits, all 256 blocks.
    // Block role: (tile2, w2, q2, lh); covers k0..k0+3 x 16 j's (64 outputs).
    f32x4* sm = (f32x4*)ExT;           // [sq][c][l16] = 16*3*16 f32x4 (12 KB)

    const int bx    = blockIdx.x;
    const int tile2 = bx >> 6;
    const int w2    = (bx >> 4) & 3;
    const int q2    = (bx >> 2) & 3;   // kt*2 + jt
    const int lh    = bx & 3;          // 16-lane quarter of the fragment
    const int l16   = t & 15;
    const int sq    = t >> 4;          // 0..15
    const int lane2 = lh * 16 + l16;

    const f16x4* basep = (const f16x4*)wsP;   // h4 units; PBLK/4 = 3072 per s
    const int slot = (w2 * 12 + q2) * 64 + lane2;

    f32x4 s0 = {0.f,0.f,0.f,0.f}, s1 = s0, s2 = s0;
#pragma unroll
    for (int s = sq * 4; s < sq * 4 + 4; ++s) {
        const size_t bo = (size_t)(tile2 * NSPLIT + s) * 3072 + slot;
        const f16x4 h0 = basep[bo];          // c=0 (channel stride 256 h4)
        const f16x4 h1 = basep[bo + 256];    // c=1
        const f16x4 h2 = basep[bo + 512];    // c=2
#pragma unroll
        for (int r = 0; r < 4; ++r) {
            s0[r] += (float)h0[r];
            s1[r] += (float)h1[r];
            s2[r] += (float)h2[r];
        }
    }
    sm[(sq * 3 + 0) * 16 + l16] = s0;
    sm[(sq * 3 + 1) * 16 + l16] = s1;
    sm[(sq * 3 + 2) * 16 + l16] = s2;
    __syncthreads();

    if (t < 16) {
        f32x4 f0 = {0.f,0.f,0.f,0.f}, f1 = f0, f2 = f0;
#pragma unroll
        for (int u = 0; u < 16; ++u) {
#pragma unroll
            for (int r = 0; r < 4; ++r) {
                f0[r] += sm[(u * 3 + 0) * 16 + t][r];
                f1[r] += sm[(u * 3 + 1) * 16 + t][r];
                f2[r] += sm[(u * 3 + 2) * 16 + t][r];
            }
        }
        const int k0 = tile2 * 32 + (q2 >> 1) * 16 + lh * 4;
        const int j  = w2 * 32 + (q2 & 1) * 16 + t;
#pragma unroll
        for (int r = 0; r < 4; ++r) {
            const int   g   = (k0 + r) * 128 + j;
            const float inv = 1.0f / f0[r];
            out[g]               = f0[r];
            out[G_TOTAL + g]     = f1[r] * inv;
            out[2 * G_TOTAL + g] = f2[r] * inv;
        }
    }
}

// ---------------------------------------------------------------------------
extern "C" void kernel_launch(void* const* d_in, const int* in_sizes, int n_in,
                              void* d_out, int out_size, void* d_ws, size_t ws_size,
                              hipStream_t stream) {
    const float* X = (const float*)d_in[0];
    const float* Y = (const float*)d_in[1];
    float* out = (float*)d_out;
    f16*  wsP = (f16*)d_ws;

    void* args[] = {(void*)&X, (void*)&Y, (void*)&wsP, (void*)&out};
    hipLaunchCooperativeKernel((void*)enc_reduce_coop,
                               dim3(256), dim3(256), args, 0, stream);
}

// Round 13
// 63.990 us; speedup vs baseline: 1.6475x; 1.6475x over previous
//
#include <hip/hip_runtime.h>

#define G_TOTAL 16384            // 128 x 128 grid
#define NPTS    8192
#define CI      128              // context points per block chunk
#define NSPLIT  64               // 8192 / CI  -> grid 256 = 1 block/CU
#define LDA     136              // LDS row pitch in halves (128 + 8 pad)
#define PBLK    12288            // partial halves per block: 4w x 12f x 64l x 4r

typedef _Float16 f16;
typedef f16  f16x8 __attribute__((ext_vector_type(8)));
typedef f16  f16x4 __attribute__((ext_vector_type(4)));
typedef float f32x4 __attribute__((ext_vector_type(4)));

// Raw v_exp_f32 — args in [-40, 0]: no denormal/range fixup needed.
__device__ __forceinline__ float fast_exp2(float x) {
#if __has_builtin(__builtin_amdgcn_exp2f)
    return __builtin_amdgcn_exp2f(x);
#else
    float r; asm("v_exp_f32 %0, %1" : "=v"(r) : "v"(x)); return r;
#endif
}

// ---------------------------------------------------------------------------
// MFMA factorized kernel (bit-identical to R10 best; enc attributed ~6us by
// the R11 double-launch probe — not the bottleneck, left untouched).
// R12 post-mortem: hipLaunchCooperativeKernel cost +41us on this harness
// (graph-capture defeat / grid-sync spin) — reverted to 2 regular launches.
// ---------------------------------------------------------------------------
__global__ __launch_bounds__(256) void enc_mfma(
    const float* __restrict__ X,   // (8192, 2) positions
    const float* __restrict__ Y,   // (8192, 2) labels
    f16* __restrict__ wsP)         // partials [tile][s][PBLK]
{
    __shared__ f16 ExT[128 * LDA];     // [j][i]    34.8 KB
    __shared__ f16 Ey3[3 * 32 * LDA];  // [c][k][i] 26.1 KB

    const int t    = threadIdx.x;
    const int b    = blockIdx.x;
    const int tile = b & 3;            // k band: kb = tile*32
    const int sidx = b >> 2;           // split 0..63
    const int c0   = sidx * CI;
    const int kb   = tile * 32;

    const float sc   = 0.84932184f;    // sqrt(0.5 * log2(e))
    const float step = 4.0f / 127.0f;

    const float2* X2 = (const float2*)X;
    const float2* Y2 = (const float2*)Y;

    // ---- stage ExT[j][i], fp16: thread -> (j = t>>1, 64-i half)
    {
        const int   j  = t >> 1, ih = (t & 1) * 64;
        const float gx = (-2.0f + step * (float)j) * sc;
#pragma unroll
        for (int u = 0; u < 8; ++u) {
            f16x8 v;
#pragma unroll
            for (int e = 0; e < 8; ++e) {
                const int   i = ih + u * 8 + e;
                const float d = gx - X2[c0 + i].x * sc;
                v[e] = (f16)fast_exp2(-d * d);
            }
            *(f16x8*)&ExT[j * LDA + ih + u * 8] = v;
        }
    }
    // ---- stage Ey3[c][k][i], channels baked: thread -> (k = t>>3, 16-i blk)
    {
        const int   k  = t >> 3, ib = (t & 7) * 16;
        const float gy = (2.0f - step * (float)(kb + k)) * sc;
#pragma unroll
        for (int u = 0; u < 2; ++u) {
            f16x8 v0, v1, v2;
#pragma unroll
            for (int e = 0; e < 8; ++e) {
                const int    i  = ib + u * 8 + e;
                const float  d  = gy - X2[c0 + i].y * sc;
                const float  ee = fast_exp2(-d * d);
                const float2 yv = Y2[c0 + i];
                v0[e] = (f16)ee;
                v1[e] = (f16)(ee * yv.x);
                v2[e] = (f16)(ee * yv.y);
            }
            *(f16x8*)&Ey3[(0 * 32 + k) * LDA + ib + u * 8] = v0;
            *(f16x8*)&Ey3[(1 * 32 + k) * LDA + ib + u * 8] = v1;
            *(f16x8*)&Ey3[(2 * 32 + k) * LDA + ib + u * 8] = v2;
        }
    }
    __syncthreads();

    // ---- MFMA: wave w owns j in [32w, 32w+32). 48 mfma per wave (4 ksteps).
    const int w    = t >> 6;
    const int lane = t & 63;
    const int l15  = lane & 15;
    const int lk8  = (lane >> 4) * 8;

    f32x4 acc[12];                     // [c*4 + kt*2 + jt]
#pragma unroll
    for (int z = 0; z < 12; ++z) acc[z] = (f32x4){0.f, 0.f, 0.f, 0.f};

#pragma unroll
    for (int ks = 0; ks < 4; ++ks) {
        const int io = ks * 32 + lk8;
        const f16x8 bf0 = *(const f16x8*)&ExT[(w * 32 +      l15) * LDA + io];
        const f16x8 bf1 = *(const f16x8*)&ExT[(w * 32 + 16 + l15) * LDA + io];
#pragma unroll
        for (int c = 0; c < 3; ++c) {
            const f16x8 a0 = *(const f16x8*)&Ey3[(c * 32 +      l15) * LDA + io];
            const f16x8 a1 = *(const f16x8*)&Ey3[(c * 32 + 16 + l15) * LDA + io];
            acc[c*4+0] = __builtin_amdgcn_mfma_f32_16x16x32_f16(a0, bf0, acc[c*4+0], 0, 0, 0);
            acc[c*4+1] = __builtin_amdgcn_mfma_f32_16x16x32_f16(a0, bf1, acc[c*4+1], 0, 0, 0);
            acc[c*4+2] = __builtin_amdgcn_mfma_f32_16x16x32_f16(a1, bf0, acc[c*4+2], 0, 0, 0);
            acc[c*4+3] = __builtin_amdgcn_mfma_f32_16x16x32_f16(a1, bf1, acc[c*4+3], 0, 0, 0);
        }
    }

    // ---- fragment-native fp16 partial store: lane-contiguous h4, coalesced.
    f16* P = wsP + (size_t)(tile * NSPLIT + sidx) * PBLK;
#pragma unroll
    for (int f = 0; f < 12; ++f) {
        f16x4 pv;
        pv[0] = (f16)acc[f][0];  pv[1] = (f16)acc[f][1];
        pv[2] = (f16)acc[f][2];  pv[3] = (f16)acc[f][3];
        *(f16x4*)&P[((w * 12 + f) * 64 + lane) * 4] = pv;
    }
}

// ---------------------------------------------------------------------------
// Reduce + normalize, 256 blocks (R12 phase-2 geometry, correctness-verified
// there; now a standalone regular launch). Block bx = (tile, w, q, lh):
// 64 outputs each. Thread (l16 = t&15, sq = t>>4) sums 4 splits x 3 channels
// (coalesced h4 loads, 12 independent loads in flight); 16-way LDS combine;
// 16 lanes normalize in-register and write 12 outputs each.
// ---------------------------------------------------------------------------
__global__ __launch_bounds__(256) void reduce_norm(
    const f16* __restrict__ wsP, float* __restrict__ out)
{
    __shared__ f32x4 sm[16 * 3 * 16];  // [sq][c][l16] : 12 KB

    const int bx    = blockIdx.x;
    const int tile  = bx >> 6;
    const int w     = (bx >> 4) & 3;
    const int q     = (bx >> 2) & 3;   // kt*2 + jt
    const int lh    = bx & 3;          // 16-lane quarter of the fragment
    const int t     = threadIdx.x;
    const int l16   = t & 15;
    const int sq    = t >> 4;          // 0..15
    const int lane2 = lh * 16 + l16;

    const f16x4* basep = (const f16x4*)wsP;  // h4 units; PBLK/4 = 3072 per s
    const int slot = (w * 12 + q) * 64 + lane2;

    f32x4 s0 = {0.f,0.f,0.f,0.f}, s1 = s0, s2 = s0;
#pragma unroll
    for (int s = sq * 4; s < sq * 4 + 4; ++s) {
        const size_t bo = (size_t)(tile * NSPLIT + s) * 3072 + slot;
        const f16x4 h0 = basep[bo];          // c=0 (channel stride 256 h4)
        const f16x4 h1 = basep[bo + 256];    // c=1
        const f16x4 h2 = basep[bo + 512];    // c=2
#pragma unroll
        for (int r = 0; r < 4; ++r) {
            s0[r] += (float)h0[r];
            s1[r] += (float)h1[r];
            s2[r] += (float)h2[r];
        }
    }
    sm[(sq * 3 + 0) * 16 + l16] = s0;
    sm[(sq * 3 + 1) * 16 + l16] = s1;
    sm[(sq * 3 + 2) * 16 + l16] = s2;
    __syncthreads();

    if (t < 16) {
        f32x4 f0 = {0.f,0.f,0.f,0.f}, f1 = f0, f2 = f0;
#pragma unroll
        for (int u = 0; u < 16; ++u) {
#pragma unroll
            for (int r = 0; r < 4; ++r) {
                f0[r] += sm[(u * 3 + 0) * 16 + t][r];
                f1[r] += sm[(u * 3 + 1) * 16 + t][r];
                f2[r] += sm[(u * 3 + 2) * 16 + t][r];
            }
        }
        const int k0 = tile * 32 + (q >> 1) * 16 + lh * 4;
        const int j  = w * 32 + (q & 1) * 16 + t;
#pragma unroll
        for (int r = 0; r < 4; ++r) {
            const int   g   = (k0 + r) * 128 + j;
            const float inv = 1.0f / f0[r];
            out[g]               = f0[r];
            out[G_TOTAL + g]     = f1[r] * inv;
            out[2 * G_TOTAL + g] = f2[r] * inv;
        }
    }
}

// ---------------------------------------------------------------------------
extern "C" void kernel_launch(void* const* d_in, const int* in_sizes, int n_in,
                              void* d_out, int out_size, void* d_ws, size_t ws_size,
                              hipStream_t stream) {
    const float* X = (const float*)d_in[0];
    const float* Y = (const float*)d_in[1];
    float* out = (float*)d_out;
    f16*  wsP = (f16*)d_ws;

    enc_mfma<<<256, 256, 0, stream>>>(X, Y, wsP);   // 1 block/CU
    reduce_norm<<<256, 256, 0, stream>>>(wsP, out); // 256 blocks, 4-deep chains
}

// Round 15
// 62.742 us; speedup vs baseline: 1.6803x; 1.0199x over previous
//
#include <hip/hip_runtime.h>

#define G_TOTAL 16384            // 128 x 128 grid
#define NPTS    8192
#define CI      128              // context points per block chunk
#define NSPLIT  64               // 8192 / CI  -> grid 256 = 1 block/CU
#define LDA     136              // LDS row pitch in halves (128 + 8 pad)
#define PBLK    12288            // partial halves per block: 4w x 12f x 64l x 4r

typedef _Float16 f16;
typedef f16  f16x8 __attribute__((ext_vector_type(8)));
typedef f16  f16x4 __attribute__((ext_vector_type(4)));
typedef float f32x4 __attribute__((ext_vector_type(4)));

// Raw v_exp_f32 — args in [-40, 0]: no denormal/range fixup needed.
__device__ __forceinline__ float fast_exp2(float x) {
#if __has_builtin(__builtin_amdgcn_exp2f)
    return __builtin_amdgcn_exp2f(x);
#else
    float r; asm("v_exp_f32 %0, %1" : "=v"(r) : "v"(x)); return r;
#endif
}

// ---------------------------------------------------------------------------
// MFMA factorized kernel (R13 core + LDS-staged inputs).
// R13 post-mortem: budget = fill 41 + enc 6 + reduce 2 + gap 1.5 + harness
// overhead ~13. Only enc is addressable. Its staging loops issued ~96
// redundant VMEM loads/thread (all j-threads re-loading the same X2[i]) at
// 1 wave/SIMD — input-load latency dominates. Fix: coalesced one-shot load
// of the block's 128 points into LDS (xs/ysn/yv2, 2KB), exp loops read
// operands via vectorized broadcast ds_reads. MFMA/store/reduce unchanged.
// ---------------------------------------------------------------------------
__global__ __launch_bounds__(256) void enc_mfma(
    const float* __restrict__ X,   // (8192, 2) positions
    const float* __restrict__ Y,   // (8192, 2) labels
    f16* __restrict__ wsP)         // partials [tile][s][PBLK]
{
    __shared__ f16 ExT[128 * LDA];     // [j][i]    34.0 KB
    __shared__ f16 Ey3[3 * 32 * LDA];  // [c][k][i] 25.5 KB
    __shared__ float  xs[CI];          // x*sc   0.5 KB
    __shared__ float  ysn[CI];         // y*sc   0.5 KB
    __shared__ float2 yv2[CI];         // labels 1.0 KB

    const int t    = threadIdx.x;
    const int b    = blockIdx.x;
    const int tile = b & 3;            // k band: kb = tile*32
    const int sidx = b >> 2;           // split 0..63
    const int c0   = sidx * CI;
    const int kb   = tile * 32;

    const float sc   = 0.84932184f;    // sqrt(0.5 * log2(e))
    const float step = 4.0f / 127.0f;

    const float2* X2 = (const float2*)X;
    const float2* Y2 = (const float2*)Y;

    // ---- one-shot coalesced input stage (2 KB)
    if (t < CI) {
        const float2 xv = X2[c0 + t];
        xs[t]  = xv.x * sc;
        ysn[t] = xv.y * sc;
        yv2[t] = Y2[c0 + t];
    }
    __syncthreads();

    // ---- stage ExT[j][i], fp16: thread -> (j = t>>1, 64-i half)
    {
        const int   j  = t >> 1, ih = (t & 1) * 64;
        const float gx = (-2.0f + step * (float)j) * sc;
#pragma unroll
        for (int u = 0; u < 8; ++u) {
            const float4 xa = *(const float4*)&xs[ih + u * 8];
            const float4 xb = *(const float4*)&xs[ih + u * 8 + 4];
            f16x8 v;
            {
                float d;
                d = gx - xa.x;  v[0] = (f16)fast_exp2(-d * d);
                d = gx - xa.y;  v[1] = (f16)fast_exp2(-d * d);
                d = gx - xa.z;  v[2] = (f16)fast_exp2(-d * d);
                d = gx - xa.w;  v[3] = (f16)fast_exp2(-d * d);
                d = gx - xb.x;  v[4] = (f16)fast_exp2(-d * d);
                d = gx - xb.y;  v[5] = (f16)fast_exp2(-d * d);
                d = gx - xb.z;  v[6] = (f16)fast_exp2(-d * d);
                d = gx - xb.w;  v[7] = (f16)fast_exp2(-d * d);
            }
            *(f16x8*)&ExT[j * LDA + ih + u * 8] = v;
        }
    }
    // ---- stage Ey3[c][k][i], channels baked: thread -> (k = t>>3, 16-i blk)
    {
        const int   k  = t >> 3, ib = (t & 7) * 16;
        const float gy = (2.0f - step * (float)(kb + k)) * sc;
#pragma unroll
        for (int u = 0; u < 2; ++u) {
            const float4 ya = *(const float4*)&ysn[ib + u * 8];
            const float4 yb = *(const float4*)&ysn[ib + u * 8 + 4];
            const float yy[8] = {ya.x, ya.y, ya.z, ya.w, yb.x, yb.y, yb.z, yb.w};
            f16x8 v0, v1, v2;
#pragma unroll
            for (int e = 0; e < 8; ++e) {
                const int    i  = ib + u * 8 + e;
                const float  d  = gy - yy[e];
                const float  ee = fast_exp2(-d * d);
                const float2 lv = yv2[i];
                v0[e] = (f16)ee;
                v1[e] = (f16)(ee * lv.x);
                v2[e] = (f16)(ee * lv.y);
            }
            *(f16x8*)&Ey3[(0 * 32 + k) * LDA + ib + u * 8] = v0;
            *(f16x8*)&Ey3[(1 * 32 + k) * LDA + ib + u * 8] = v1;
            *(f16x8*)&Ey3[(2 * 32 + k) * LDA + ib + u * 8] = v2;
        }
    }
    __syncthreads();

    // ---- MFMA: wave w owns j in [32w, 32w+32). 48 mfma per wave (4 ksteps).
    const int w    = t >> 6;
    const int lane = t & 63;
    const int l15  = lane & 15;
    const int lk8  = (lane >> 4) * 8;

    f32x4 acc[12];                     // [c*4 + kt*2 + jt]
#pragma unroll
    for (int z = 0; z < 12; ++z) acc[z] = (f32x4){0.f, 0.f, 0.f, 0.f};

#pragma unroll
    for (int ks = 0; ks < 4; ++ks) {
        const int io = ks * 32 + lk8;
        const f16x8 bf0 = *(const f16x8*)&ExT[(w * 32 +      l15) * LDA + io];
        const f16x8 bf1 = *(const f16x8*)&ExT[(w * 32 + 16 + l15) * LDA + io];
#pragma unroll
        for (int c = 0; c < 3; ++c) {
            const f16x8 a0 = *(const f16x8*)&Ey3[(c * 32 +      l15) * LDA + io];
            const f16x8 a1 = *(const f16x8*)&Ey3[(c * 32 + 16 + l15) * LDA + io];
            acc[c*4+0] = __builtin_amdgcn_mfma_f32_16x16x32_f16(a0, bf0, acc[c*4+0], 0, 0, 0);
            acc[c*4+1] = __builtin_amdgcn_mfma_f32_16x16x32_f16(a0, bf1, acc[c*4+1], 0, 0, 0);
            acc[c*4+2] = __builtin_amdgcn_mfma_f32_16x16x32_f16(a1, bf0, acc[c*4+2], 0, 0, 0);
            acc[c*4+3] = __builtin_amdgcn_mfma_f32_16x16x32_f16(a1, bf1, acc[c*4+3], 0, 0, 0);
        }
    }

    // ---- fragment-native fp16 partial store: lane-contiguous h4, coalesced.
    f16* P = wsP + (size_t)(tile * NSPLIT + sidx) * PBLK;
#pragma unroll
    for (int f = 0; f < 12; ++f) {
        f16x4 pv;
        pv[0] = (f16)acc[f][0];  pv[1] = (f16)acc[f][1];
        pv[2] = (f16)acc[f][2];  pv[3] = (f16)acc[f][3];
        *(f16x4*)&P[((w * 12 + f) * 64 + lane) * 4] = pv;
    }
}

// ---------------------------------------------------------------------------
// Reduce + normalize, 256 blocks (identical to R13). Block bx =
// (tile, w, q, lh): 64 outputs. Thread (l16, sq) sums 4 splits x 3 channels;
// 16-way LDS combine; 16 lanes normalize + write 12 outputs each.
// ---------------------------------------------------------------------------
__global__ __launch_bounds__(256) void reduce_norm(
    const f16* __restrict__ wsP, float* __restrict__ out)
{
    __shared__ f32x4 sm[16 * 3 * 16];  // [sq][c][l16] : 12 KB

    const int bx    = blockIdx.x;
    const int tile  = bx >> 6;
    const int w     = (bx >> 4) & 3;
    const int q     = (bx >> 2) & 3;   // kt*2 + jt
    const int lh    = bx & 3;          // 16-lane quarter of the fragment
    const int t     = threadIdx.x;
    const int l16   = t & 15;
    const int sq    = t >> 4;          // 0..15
    const int lane2 = lh * 16 + l16;

    const f16x4* basep = (const f16x4*)wsP;  // h4 units; PBLK/4 = 3072 per s
    const int slot = (w * 12 + q) * 64 + lane2;

    f32x4 s0 = {0.f,0.f,0.f,0.f}, s1 = s0, s2 = s0;
#pragma unroll
    for (int s = sq * 4; s < sq * 4 + 4; ++s) {
        const size_t bo = (size_t)(tile * NSPLIT + s) * 3072 + slot;
        const f16x4 h0 = basep[bo];          // c=0 (channel stride 256 h4)
        const f16x4 h1 = basep[bo + 256];    // c=1
        const f16x4 h2 = basep[bo + 512];    // c=2
#pragma unroll
        for (int r = 0; r < 4; ++r) {
            s0[r] += (float)h0[r];
            s1[r] += (float)h1[r];
            s2[r] += (float)h2[r];
        }
    }
    sm[(sq * 3 + 0) * 16 + l16] = s0;
    sm[(sq * 3 + 1) * 16 + l16] = s1;
    sm[(sq * 3 + 2) * 16 + l16] = s2;
    __syncthreads();

    if (t < 16) {
        f32x4 f0 = {0.f,0.f,0.f,0.f}, f1 = f0, f2 = f0;
#pragma unroll
        for (int u = 0; u < 16; ++u) {
#pragma unroll
            for (int r = 0; r < 4; ++r) {
                f0[r] += sm[(u * 3 + 0) * 16 + t][r];
                f1[r] += sm[(u * 3 + 1) * 16 + t][r];
                f2[r] += sm[(u * 3 + 2) * 16 + t][r];
            }
        }
        const int k0 = tile * 32 + (q >> 1) * 16 + lh * 4;
        const int j  = w * 32 + (q & 1) * 16 + t;
#pragma unroll
        for (int r = 0; r < 4; ++r) {
            const int   g   = (k0 + r) * 128 + j;
            const float inv = 1.0f / f0[r];
            out[g]               = f0[r];
            out[G_TOTAL + g]     = f1[r] * inv;
            out[2 * G_TOTAL + g] = f2[r] * inv;
        }
    }
}

// ---------------------------------------------------------------------------
extern "C" void kernel_launch(void* const* d_in, const int* in_sizes, int n_in,
                              void* d_out, int out_size, void* d_ws, size_t ws_size,
                              hipStream_t stream) {
    const float* X = (const float*)d_in[0];
    const float* Y = (const float*)d_in[1];
    float* out = (float*)d_out;
    f16*  wsP = (f16*)d_ws;

    enc_mfma<<<256, 256, 0, stream>>>(X, Y, wsP);   // 1 block/CU
    reduce_norm<<<256, 256, 0, stream>>>(wsP, out); // 256 blocks, 4-deep chains
}